// Round 6
// baseline (2521.236 us; speedup 1.0000x reference)
//
#include <hip/hip_runtime.h>
#include <hip/hip_fp16.h>
#include <stdint.h>

#define B_TOTAL 1024
#define T_TOTAL 1024
#define LOG2E 1.44269504088896f

typedef _Float16 f16x2 __attribute__((ext_vector_type(2)));

__device__ __forceinline__ float dot2acc(uint32_t xw, f16x2 w, float acc) {
#if __has_builtin(__builtin_amdgcn_fdot2)
    return __builtin_amdgcn_fdot2(__builtin_bit_cast(f16x2, xw), w, acc, false);
#else
    f16x2 xv = __builtin_bit_cast(f16x2, xw);
    return acc + (float)xv.x * (float)w.x + (float)xv.y * (float)w.y;
#endif
}

__device__ __forceinline__ uint32_t packf2(float a, float b) {
    f16x2 t;
    t.x = (_Float16)a;
    t.y = (_Float16)b;
    return __builtin_bit_cast(uint32_t, t);
}

__device__ __forceinline__ float sigm_(float z) {
    float e = __builtin_amdgcn_exp2f(-LOG2E * z);
    return __builtin_amdgcn_rcpf(1.0f + e);
}
__device__ __forceinline__ float tanh_(float z) {
    float e = __builtin_amdgcn_exp2f((2.0f * LOG2E) * z);
    float r = __builtin_amdgcn_rcpf(1.0f + e);
    return __builtin_fmaf(-2.0f, r, 1.0f);
}

__device__ __forceinline__ void wavebar() {
#if __has_builtin(__builtin_amdgcn_wave_barrier)
    __builtin_amdgcn_wave_barrier();
#endif
}

// ======================= chunked gate pre-GEMM =======================
// Computes gate preactivations for a T-chunk: dir0 for global t in
// [t0_d0, t0_d0+tn), dir1 for [t0_d1-tn+1, t0_d1] (descending).
// G layout: Gd = G + dir*dirstride; Gd[(ct*1024+b)*2H + c] = f16x2 where
// c = 2*j+p: p0 -> (i_j, f_j), p1 -> (g_j, o_j). Bias folded.
template <int D, int H, int NDIR, bool LAYER1>
__global__ void __launch_bounds__(320) gemmc(
    const float* __restrict__ x,              // LAYER1: [B][T][8] f32
    const __half* __restrict__ inact,         // else: [T*B][D] f16
    const float* __restrict__ wf, const float* __restrict__ bfi, const float* __restrict__ bfh,
    const float* __restrict__ wb, const float* __restrict__ bbi, const float* __restrict__ bbh,
    uint32_t* __restrict__ G, int dirstride_dw, int t0_d0, int t0_d1, int tn)
{
    constexpr int COLS = 2 * H;
    constexpr int YS   = 320 / COLS;
    constexpr int NDW  = D / 2;

    const int dir = (NDIR == 2) ? blockIdx.y : 0;
    const int tid = threadIdx.x;
    const int c   = tid % COLS;
    const int s   = tid / COLS;
    const int j   = c >> 1;
    const int p   = c & 1;
    const int r0  = p * 2 * H + j;
    const int r1  = r0 + H;

    const float* w  = (NDIR == 2 && dir) ? wb : wf;
    const float* bi = (NDIR == 2 && dir) ? bbi : bfi;
    const float* bh = (NDIR == 2 && dir) ? bbh : bfh;
    const int t0  = (NDIR == 2 && dir) ? t0_d1 : t0_d0;
    const int sgn = (NDIR == 2 && dir) ? -1 : 1;

    f16x2 w0[NDW], w1[NDW];
#pragma unroll
    for (int d = 0; d < NDW; ++d) {
        f16x2 t0v, t1v;
        t0v.x = (_Float16)w[r0 * D + 2 * d];
        t0v.y = (_Float16)w[r0 * D + 2 * d + 1];
        t1v.x = (_Float16)w[r1 * D + 2 * d];
        t1v.y = (_Float16)w[r1 * D + 2 * d + 1];
        w0[d] = t0v;
        w1[d] = t1v;
    }
    const float bias0 = bi[r0] + bh[r0];
    const float bias1 = bi[r1] + bh[r1];

    uint32_t* Gd = G + (size_t)dir * dirstride_dw;
    const int rows = tn * B_TOTAL;

    for (int row = blockIdx.x * YS + s; row < rows; row += gridDim.x * YS) {
        const int ct = row >> 10;
        const int b  = row & 1023;
        const int gt = t0 + sgn * ct;

        uint32_t xr[NDW];
        if constexpr (LAYER1) {
            const float* xp = x + ((size_t)b * T_TOTAL + gt) * 8;
            float4 f0 = ((const float4*)xp)[0];
            float4 f1 = ((const float4*)xp)[1];
            float4 l0 = {0, 0, 0, 0}, l1 = {0, 0, 0, 0};
            if (gt > 0) {
                l0 = ((const float4*)(xp - 8))[0];
                l1 = ((const float4*)(xp - 8))[1];
            }
            xr[0] = packf2(f0.x, f0.y); xr[1] = packf2(f0.z, f0.w);
            xr[2] = packf2(f1.x, f1.y); xr[3] = packf2(f1.z, f1.w);
            xr[4] = packf2(l0.x, l0.y); xr[5] = packf2(l0.z, l0.w);
            xr[6] = packf2(l1.x, l1.y); xr[7] = packf2(l1.z, l1.w);
        } else {
            const uint32_t* ip = (const uint32_t*)(inact + ((size_t)gt * B_TOTAL + b) * D);
            if constexpr ((NDW % 4) == 0) {
#pragma unroll
                for (int q4 = 0; q4 < NDW / 4; ++q4) {
                    uint4 v = ((const uint4*)ip)[q4];
                    xr[4 * q4] = v.x; xr[4 * q4 + 1] = v.y;
                    xr[4 * q4 + 2] = v.z; xr[4 * q4 + 3] = v.w;
                }
            } else {
#pragma unroll
                for (int q2 = 0; q2 < NDW / 2; ++q2) {
                    uint2 v = ((const uint2*)ip)[q2];
                    xr[2 * q2] = v.x; xr[2 * q2 + 1] = v.y;
                }
            }
        }

        float d0 = bias0, d1 = bias1;
#pragma unroll
        for (int d = 0; d < NDW; ++d) {
            d0 = dot2acc(xr[d], w0[d], d0);
            d1 = dot2acc(xr[d], w1[d], d1);
        }
        Gd[(size_t)row * COLS + c] = packf2(d0, d1);
    }
}

// ======================= chunked slim scan =======================
// Lane = (group g, unit j), all 4 gates per lane; h all-gather via __shfl
// (no LDS, no barriers). Processes tn steps of a chunk; (h,c) state persists
// in global f32 between chunk launches.
template <int H, int NDIR, bool STORE_ALL>
__global__ void __launch_bounds__(64, 1) scan2c(
    const uint32_t* __restrict__ G, int dirstride_dw,
    const float* __restrict__ whhf, const float* __restrict__ whhb,
    __half* __restrict__ outact,              // STORE_ALL: [T][B][2H] f16
    float* __restrict__ state,                // [NDIR][B][H][2] f32
    float* __restrict__ lasth,                // !STORE_ALL: [B][H] f32
    int t0_d0, int t0_d1, int tn, int initflag)
{
    constexpr int GPW = 64 / H;
    constexpr int NH  = H / 2;
    constexpr int NGD = 2 * H;

    const int dir  = (NDIR == 2) ? blockIdx.y : 0;
    const int lane = threadIdx.x;
    const int g    = lane / H;
    const int j    = lane - g * H;
    const int b    = blockIdx.x * GPW + g;
    const bool valid = (g < GPW) && (b < B_TOTAL);
    const int bs    = valid ? b : (B_TOTAL - 1);
    const int gbase = (g < GPW ? g : (GPW - 1)) * H;   // shfl source base, in-range

    const float* w_hh = dir ? whhb : whhf;
    const int t0  = dir ? t0_d1 : t0_d0;
    const int sgn = dir ? -1 : 1;

    f16x2 whh2[4][NH];
#pragma unroll
    for (int q = 0; q < 4; ++q) {
        const int r = q * H + j;
#pragma unroll
        for (int k = 0; k < NH; ++k) {
            f16x2 t;
            t.x = (_Float16)w_hh[r * H + 2 * k];
            t.y = (_Float16)w_hh[r * H + 2 * k + 1];
            whh2[q][k] = t;
        }
    }

    const uint32_t* gp = G + (size_t)dir * dirstride_dw + (size_t)bs * NGD + 2 * j;
    const size_t gstep = (size_t)B_TOTAL * NGD;

    __half* op = nullptr;
    ptrdiff_t opstep = 0;
    if constexpr (STORE_ALL) {
        op = outact + ((size_t)t0 * B_TOTAL + bs) * (2 * H) + dir * H + j;
        opstep = (ptrdiff_t)sgn * (B_TOTAL * 2 * H);
    }

    float* sp = state + (((size_t)dir * B_TOTAL + bs) * H + j) * 2;
    float h, c;
    if (initflag) { h = 0.0f; c = 0.0f; }
    else          { h = sp[0]; c = sp[1]; }

    uint2 qb[4];
#pragma unroll
    for (int s = 0; s < 3; ++s) {      // tn >= 4 always
        qb[s] = *(const uint2*)gp;
        gp += gstep;
    }

    auto step = [&](const uint2 qc, uint2& qn, bool pf) {
        // all-gather h across the group via shfl (ds_bpermute), pack to f16x2
        uint32_t hd[NH];
#pragma unroll
        for (int k = 0; k < NH; ++k) {
            float v0 = __shfl(h, gbase + 2 * k, 64);
            float v1 = __shfl(h, gbase + 2 * k + 1, 64);
            hd[k] = packf2(v0, v1);
        }

        f16x2 lo = __builtin_bit_cast(f16x2, qc.x);
        f16x2 hi = __builtin_bit_cast(f16x2, qc.y);
        float a0 = (float)lo.x, a1 = (float)lo.y;
        float a2 = (float)hi.x, a3 = (float)hi.y;

        if (pf) { qn = *(const uint2*)gp; gp += gstep; }

#pragma unroll
        for (int k = 0; k < NH; ++k) {
            a0 = dot2acc(hd[k], whh2[0][k], a0);
            a1 = dot2acc(hd[k], whh2[1][k], a1);
            a2 = dot2acc(hd[k], whh2[2][k], a2);
            a3 = dot2acc(hd[k], whh2[3][k], a3);
        }
        const float iv = sigm_(a0);
        const float fv = sigm_(a1);
        const float gv = tanh_(a2);
        const float ov = sigm_(a3);
        c = __builtin_fmaf(fv, c, iv * gv);
        h = ov * tanh_(c);
        if constexpr (STORE_ALL) {
            if (valid) *op = __float2half(h);
            op += opstep;
        }
    };

    for (int t = 0; t < tn; t += 4) {   // tn % 4 == 0
        step(qb[0], qb[3], t + 3 < tn);
        step(qb[1], qb[0], t + 4 < tn);
        step(qb[2], qb[1], t + 5 < tn);
        step(qb[3], qb[2], t + 6 < tn);
    }

    if constexpr (STORE_ALL) {
        if (valid) { sp[0] = h; sp[1] = c; }
    } else {
        if (valid) lasth[b * H + j] = h;
    }
}

// ======================= fused fallback scan (round-4, for L2 small-ws) =======================
template <int DIN, int H, bool LAYER1, bool STORE_ALL>
__global__ void __launch_bounds__(64, 1) lstm_scan(
    const float* __restrict__ x,
    const __half* __restrict__ inbuf,
    const float* __restrict__ wihf, const float* __restrict__ whhf,
    const float* __restrict__ bihf, const float* __restrict__ bhhf,
    const float* __restrict__ wihb, const float* __restrict__ whhb,
    const float* __restrict__ bihb, const float* __restrict__ bhhb,
    __half* __restrict__ outbuf,
    float* __restrict__ lasth)
{
    constexpr int GPW   = 64 / H;
    constexpr int ND    = DIN / 2;
    constexpr int NH    = H / 2;
    constexpr int HS_DW = (H == 20) ? 12 : 8;

    const int dir  = blockIdx.y;
    const int lane = threadIdx.x;
    const int g    = lane / H;
    const int j    = lane - g * H;
    const int b    = blockIdx.x * GPW + g;
    const bool valid = (g < GPW) && (b < B_TOTAL);
    const int bs   = valid ? b : (B_TOTAL - 1);

    const float* w_ih = dir ? wihb : wihf;
    const float* w_hh = dir ? whhb : whhf;
    const float* b_ih = dir ? bihb : bihf;
    const float* b_hh = dir ? bhhb : bhhf;

    __shared__ uint32_t hsm[GPW + 1][HS_DW];

    f16x2 wih2[4][ND];
    f16x2 whh2[4][NH];
    float bias[4];
#pragma unroll
    for (int q = 0; q < 4; ++q) {
        const int r = q * H + j;
#pragma unroll
        for (int d = 0; d < ND; ++d) {
            f16x2 t;
            t.x = (_Float16)w_ih[r * DIN + 2 * d];
            t.y = (_Float16)w_ih[r * DIN + 2 * d + 1];
            wih2[q][d] = t;
        }
#pragma unroll
        for (int k = 0; k < NH; ++k) {
            f16x2 t;
            t.x = (_Float16)w_hh[r * H + 2 * k];
            t.y = (_Float16)w_hh[r * H + 2 * k + 1];
            whh2[q][k] = t;
        }
        bias[q] = b_ih[r] + b_hh[r];
    }

    const int tstep = dir ? -1 : 1;
    int tt = dir ? (T_TOTAL - 1) : 0;

    __half* op = nullptr;
    ptrdiff_t opstep = 0;
    if constexpr (STORE_ALL) {
        op = outbuf + (size_t)tt * (B_TOTAL * 2 * H) + (size_t)bs * (2 * H) + dir * H + j;
        opstep = (ptrdiff_t)tstep * (B_TOTAL * 2 * H);
    }

    float c = 0.0f;
    float hlast = 0.0f;
    ((__half*)&hsm[g][0])[j] = __float2half(0.0f);
    wavebar();

    auto tail = [&](const uint32_t* hd, float a0, float a1, float a2, float a3) {
#pragma unroll
        for (int k = 0; k < NH; ++k) {
            a0 = dot2acc(hd[k], whh2[0][k], a0);
            a1 = dot2acc(hd[k], whh2[1][k], a1);
            a2 = dot2acc(hd[k], whh2[2][k], a2);
            a3 = dot2acc(hd[k], whh2[3][k], a3);
        }
        const float iv = sigm_(a0);
        const float fv = sigm_(a1);
        const float gv = tanh_(a2);
        const float ov = sigm_(a3);
        c = __builtin_fmaf(fv, c, iv * gv);
        const float h = ov * tanh_(c);
        ((__half*)&hsm[g][0])[j] = __float2half(h);
        wavebar();
        if constexpr (STORE_ALL) {
            if (valid) *op = __float2half(h);
            op += opstep;
        } else {
            hlast = h;
        }
        tt += tstep;
    };

    {
        const ptrdiff_t ipstep = (ptrdiff_t)tstep * (B_TOTAL * ND);
        const uint32_t* ip = (const uint32_t*)inbuf + (size_t)tt * (B_TOTAL * ND) + (size_t)bs * ND;

        uint32_t xb[4][ND];
#pragma unroll
        for (int s = 0; s < 3; ++s) {
#pragma unroll
            for (int d = 0; d < ND; ++d) xb[s][d] = ip[d];
            ip += ipstep;
        }

        auto stp = [&](const uint32_t* xc, uint32_t* xn, bool pf) {
            uint32_t hd[NH];
#pragma unroll
            for (int k = 0; k < NH; ++k) hd[k] = hsm[g][k];

            float a0 = bias[0], a1 = bias[1], a2 = bias[2], a3 = bias[3];
#pragma unroll
            for (int d = 0; d < ND; ++d) {
                a0 = dot2acc(xc[d], wih2[0][d], a0);
                a1 = dot2acc(xc[d], wih2[1][d], a1);
                a2 = dot2acc(xc[d], wih2[2][d], a2);
                a3 = dot2acc(xc[d], wih2[3][d], a3);
            }
            if (pf) {
#pragma unroll
                for (int d = 0; d < ND; ++d) xn[d] = ip[d];
                ip += ipstep;
            }
            tail(hd, a0, a1, a2, a3);
        };

        for (int t = 0; t < T_TOTAL; t += 4) {
            stp(xb[0], xb[3], t + 3 < T_TOTAL);
            stp(xb[1], xb[0], t + 4 < T_TOTAL);
            stp(xb[2], xb[1], t + 5 < T_TOTAL);
            stp(xb[3], xb[2], t + 6 < T_TOTAL);
        }
    }

    if constexpr (!STORE_ALL) {
        if (valid) lasth[b * H + j] = hlast;
    }
}

// L4 backward needed only at t=T-1 (single step from zero state) + FC + sigmoid.
__global__ void final_kernel(const __half* __restrict__ l3out,  // [T][B][20] f16
                             const float* __restrict__ hf4,     // [B][10]
                             const float* __restrict__ w_ih,    // w4b_ih [40][20]
                             const float* __restrict__ b_ih,
                             const float* __restrict__ b_hh,
                             const float* __restrict__ fc_w,    // [20]
                             const float* __restrict__ fc_b,
                             float* __restrict__ out)           // [B]
{
    const int b = blockIdx.x * blockDim.x + threadIdx.x;
    if (b >= B_TOTAL) return;

    float in4[20];
    const __half* p = l3out + (size_t)(T_TOTAL - 1) * (B_TOTAL * 20) + (size_t)b * 20;
#pragma unroll
    for (int i = 0; i < 20; ++i) in4[i] = __half2float(p[i]);

    float z = fc_b[0];
#pragma unroll
    for (int k = 0; k < 10; ++k) z += fc_w[k] * hf4[b * 10 + k];

#pragma unroll
    for (int k = 0; k < 10; ++k) {
        float gi = b_ih[k]      + b_hh[k];
        float gg = b_ih[20 + k] + b_hh[20 + k];
        float go = b_ih[30 + k] + b_hh[30 + k];
#pragma unroll
        for (int i = 0; i < 20; ++i) {
            const float xi = in4[i];
            gi += w_ih[k * 20 + i]        * xi;
            gg += w_ih[(20 + k) * 20 + i] * xi;
            go += w_ih[(30 + k) * 20 + i] * xi;
        }
        const float cc = sigm_(gi) * tanh_(gg);
        const float hb = sigm_(go) * tanh_(cc);
        z += fc_w[10 + k] * hb;
    }
    out[b] = sigm_(z);
}

extern "C" void kernel_launch(void* const* d_in, const int* in_sizes, int n_in,
                              void* d_out, int out_size, void* d_ws, size_t ws_size,
                              hipStream_t stream) {
    const float* x = (const float*)d_in[0];
    auto W = [&](int li, int dr, int k) -> const float* {
        return (const float*)d_in[1 + (li - 1) * 8 + dr * 4 + k];
    };
    const float* fc_w = (const float*)d_in[33];
    const float* fc_b = (const float*)d_in[34];
    float* out = (float*)d_out;

    constexpr size_t MB = 1ull << 20;
    char* w8 = (char*)d_ws;
    // Overlay map (fits in 160 MiB):
    //  A0 [0,80MB)   : act buffer (L1 out, later L3 out in [0,40MB))
    //  A1 [80,160MB) : act buffer (L2 out); doubles as G1 (L1 gates) and G4
    //  G1 = A1 base (75MB), ST1 = +156MB ; G3 = +40MB (37.5MB), ST3 = +78MB
    //  HF4 = +79MB ; G4 = A1 (80MB full-T) ; big-ws only: G2 = +160MB, ST2 = +236MB
    __half*   A0  = (__half*)w8;
    __half*   A1  = (__half*)(w8 + 80 * MB);
    uint32_t* G1  = (uint32_t*)(w8 + 80 * MB);
    float*    ST1 = (float*)(w8 + 156 * MB);
    uint32_t* G3  = (uint32_t*)(w8 + 40 * MB);
    float*    ST3 = (float*)(w8 + 78 * MB);
    float*    HF4 = (float*)(w8 + 79 * MB);
    uint32_t* G4  = (uint32_t*)(w8 + 80 * MB);
    uint32_t* G2  = (uint32_t*)(w8 + 160 * MB);
    float*    ST2 = (float*)(w8 + 236 * MB);
    const bool bigws = ws_size >= 238 * MB;

    const int chs[5] = {240, 240, 240, 240, 64};

    // ---- Layer 1: D=16 (x+lag), H=20, G in A1 ----
    {
        int t0a = 0, t0b = T_TOTAL - 1;
        for (int i = 0; i < 5; ++i) {
            const int tn = chs[i];
            const int ds = tn * B_TOTAL * 40;
            gemmc<16, 20, 2, true><<<dim3(1536, 2), 320, 0, stream>>>(
                x, nullptr,
                W(1,0,0), W(1,0,2), W(1,0,3),
                W(1,1,0), W(1,1,2), W(1,1,3),
                G1, ds, t0a, t0b, tn);
            scan2c<20, 2, true><<<dim3(342, 2), 64, 0, stream>>>(
                G1, ds, W(1,0,1), W(1,1,1), A0, ST1, nullptr, t0a, t0b, tn, i == 0);
            t0a += tn; t0b -= tn;
        }
    }

    // ---- Layer 2: D=40, H=20 ----
    if (bigws) {
        int t0a = 0, t0b = T_TOTAL - 1;
        for (int i = 0; i < 5; ++i) {
            const int tn = chs[i];
            const int ds = tn * B_TOTAL * 40;
            gemmc<40, 20, 2, false><<<dim3(1536, 2), 320, 0, stream>>>(
                nullptr, A0,
                W(2,0,0), W(2,0,2), W(2,0,3),
                W(2,1,0), W(2,1,2), W(2,1,3),
                G2, ds, t0a, t0b, tn);
            scan2c<20, 2, true><<<dim3(342, 2), 64, 0, stream>>>(
                G2, ds, W(2,0,1), W(2,1,1), A1, ST2, nullptr, t0a, t0b, tn, i == 0);
            t0a += tn; t0b -= tn;
        }
    } else {
        lstm_scan<40, 20, false, true><<<dim3(342, 2), 64, 0, stream>>>(
            nullptr, A0,
            W(2,0,0), W(2,0,1), W(2,0,2), W(2,0,3),
            W(2,1,0), W(2,1,1), W(2,1,2), W(2,1,3),
            A1, nullptr);
    }

    // ---- Layer 3: D=40, H=10, out -> A0[0,40MB), G in A0[40,77.5MB) ----
    {
        int t0a = 0, t0b = T_TOTAL - 1;
        for (int i = 0; i < 5; ++i) {
            const int tn = chs[i];
            const int ds = tn * B_TOTAL * 20;
            gemmc<40, 10, 2, false><<<dim3(1536, 2), 320, 0, stream>>>(
                nullptr, A1,
                W(3,0,0), W(3,0,2), W(3,0,3),
                W(3,1,0), W(3,1,2), W(3,1,3),
                G3, ds, t0a, t0b, tn);
            scan2c<10, 2, true><<<dim3(171, 2), 64, 0, stream>>>(
                G3, ds, W(3,0,1), W(3,1,1), A0, ST3, nullptr, t0a, t0b, tn, i == 0);
            t0a += tn; t0b -= tn;
        }
    }

    // ---- Layer 4 fwd only: D=20, H=10, full-T G in A1 ----
    gemmc<20, 10, 1, false><<<dim3(1536, 1), 320, 0, stream>>>(
        nullptr, A0,
        W(4,0,0), W(4,0,2), W(4,0,3),
        W(4,0,0), W(4,0,2), W(4,0,3),
        G4, 0, 0, 0, T_TOTAL);
    scan2c<10, 1, false><<<dim3(171, 1), 64, 0, stream>>>(
        G4, 0, W(4,0,1), W(4,0,1), nullptr, HF4, HF4, 0, 0, T_TOTAL, 1);

    // ---- L4 backward single step + FC + sigmoid ----
    final_kernel<<<dim3(4, 1, 1), 256, 0, stream>>>(
        A0, HF4, W(4,1,0), W(4,1,2), W(4,1,3), fc_w, fc_b, out);
}

// Round 7
// 2431.533 us; speedup vs baseline: 1.0369x; 1.0369x over previous
//
#include <hip/hip_runtime.h>
#include <hip/hip_fp16.h>
#include <stdint.h>

#define B_TOTAL 1024
#define T_TOTAL 1024
#define LOG2E 1.44269504088896f

typedef _Float16 f16x2 __attribute__((ext_vector_type(2)));

__device__ __forceinline__ float dot2acc(uint32_t xw, f16x2 w, float acc) {
#if __has_builtin(__builtin_amdgcn_fdot2)
    return __builtin_amdgcn_fdot2(__builtin_bit_cast(f16x2, xw), w, acc, false);
#else
    f16x2 xv = __builtin_bit_cast(f16x2, xw);
    return acc + (float)xv.x * (float)w.x + (float)xv.y * (float)w.y;
#endif
}

__device__ __forceinline__ uint32_t packf2(float a, float b) {
    f16x2 t;
    t.x = (_Float16)a;
    t.y = (_Float16)b;
    return __builtin_bit_cast(uint32_t, t);
}

__device__ __forceinline__ float sigm_(float z) {
    float e = __builtin_amdgcn_exp2f(-LOG2E * z);
    return __builtin_amdgcn_rcpf(1.0f + e);
}
__device__ __forceinline__ float tanh_(float z) {
    float e = __builtin_amdgcn_exp2f((2.0f * LOG2E) * z);
    float r = __builtin_amdgcn_rcpf(1.0f + e);
    return __builtin_fmaf(-2.0f, r, 1.0f);
}

__device__ __forceinline__ void wavebar() {
#if __has_builtin(__builtin_amdgcn_wave_barrier)
    __builtin_amdgcn_wave_barrier();
#endif
}

// ======================= chunked gate pre-GEMM =======================
// dir0: global t in [t0_d0, t0_d0+tn); dir1: [t0_d1-tn+1, t0_d1] descending.
// Gd = G + dir*dirstride; Gd[(ct*1024+b)*2H + c] = f16x2, c = 2*j+p:
// p0 -> (i_j, f_j), p1 -> (g_j, o_j). Bias folded.
template <int D, int H, int NDIR, bool LAYER1>
__global__ void __launch_bounds__(320) gemmc(
    const float* __restrict__ x,              // LAYER1: [B][T][8] f32
    const __half* __restrict__ inact,         // else: [T*B][D] f16
    const float* __restrict__ wf, const float* __restrict__ bfi, const float* __restrict__ bfh,
    const float* __restrict__ wb, const float* __restrict__ bbi, const float* __restrict__ bbh,
    uint32_t* __restrict__ G, int dirstride_dw, int t0_d0, int t0_d1, int tn)
{
    constexpr int COLS = 2 * H;
    constexpr int YS   = 320 / COLS;
    constexpr int NDW  = D / 2;

    const int dir = (NDIR == 2) ? blockIdx.y : 0;
    const int tid = threadIdx.x;
    const int c   = tid % COLS;
    const int s   = tid / COLS;
    const int j   = c >> 1;
    const int p   = c & 1;
    const int r0  = p * 2 * H + j;
    const int r1  = r0 + H;

    const float* w  = (NDIR == 2 && dir) ? wb : wf;
    const float* bi = (NDIR == 2 && dir) ? bbi : bfi;
    const float* bh = (NDIR == 2 && dir) ? bbh : bfh;
    const int t0  = (NDIR == 2 && dir) ? t0_d1 : t0_d0;
    const int sgn = (NDIR == 2 && dir) ? -1 : 1;

    f16x2 w0[NDW], w1[NDW];
#pragma unroll
    for (int d = 0; d < NDW; ++d) {
        f16x2 t0v, t1v;
        t0v.x = (_Float16)w[r0 * D + 2 * d];
        t0v.y = (_Float16)w[r0 * D + 2 * d + 1];
        t1v.x = (_Float16)w[r1 * D + 2 * d];
        t1v.y = (_Float16)w[r1 * D + 2 * d + 1];
        w0[d] = t0v;
        w1[d] = t1v;
    }
    const float bias0 = bi[r0] + bh[r0];
    const float bias1 = bi[r1] + bh[r1];

    uint32_t* Gd = G + (size_t)dir * dirstride_dw;
    const int rows = tn * B_TOTAL;

    for (int row = blockIdx.x * YS + s; row < rows; row += gridDim.x * YS) {
        const int ct = row >> 10;
        const int b  = row & 1023;
        const int gt = t0 + sgn * ct;

        uint32_t xr[NDW];
        if constexpr (LAYER1) {
            const float* xp = x + ((size_t)b * T_TOTAL + gt) * 8;
            float4 f0 = ((const float4*)xp)[0];
            float4 f1 = ((const float4*)xp)[1];
            float4 l0 = {0, 0, 0, 0}, l1 = {0, 0, 0, 0};
            if (gt > 0) {
                l0 = ((const float4*)(xp - 8))[0];
                l1 = ((const float4*)(xp - 8))[1];
            }
            xr[0] = packf2(f0.x, f0.y); xr[1] = packf2(f0.z, f0.w);
            xr[2] = packf2(f1.x, f1.y); xr[3] = packf2(f1.z, f1.w);
            xr[4] = packf2(l0.x, l0.y); xr[5] = packf2(l0.z, l0.w);
            xr[6] = packf2(l1.x, l1.y); xr[7] = packf2(l1.z, l1.w);
        } else {
            const uint32_t* ip = (const uint32_t*)(inact + ((size_t)gt * B_TOTAL + b) * D);
            if constexpr ((NDW % 4) == 0) {
#pragma unroll
                for (int q4 = 0; q4 < NDW / 4; ++q4) {
                    uint4 v = ((const uint4*)ip)[q4];
                    xr[4 * q4] = v.x; xr[4 * q4 + 1] = v.y;
                    xr[4 * q4 + 2] = v.z; xr[4 * q4 + 3] = v.w;
                }
            } else {
#pragma unroll
                for (int q2 = 0; q2 < NDW / 2; ++q2) {
                    uint2 v = ((const uint2*)ip)[q2];
                    xr[2 * q2] = v.x; xr[2 * q2 + 1] = v.y;
                }
            }
        }

        float d0 = bias0, d1 = bias1;
#pragma unroll
        for (int d = 0; d < NDW; ++d) {
            d0 = dot2acc(xr[d], w0[d], d0);
            d1 = dot2acc(xr[d], w1[d], d1);
        }
        Gd[(size_t)row * COLS + c] = packf2(d0, d1);
    }
}

// ======================= chunked slim scan, 8-deep prefetch ring =======================
// Lane = (group g, hidden unit j); all 4 gates per lane; h all-gather via shfl.
// Gate stream prefetched 8 steps ahead (ring of uint2) to cover ~900-cyc miss
// latency (round-6: depth 3 left ~370 cyc/step exposed; VALUBusy 7.3%).
template <int H, int NDIR, bool STORE_ALL>
__global__ void __launch_bounds__(64, 1) scan2c(
    const uint32_t* __restrict__ G, int dirstride_dw,
    const float* __restrict__ whhf, const float* __restrict__ whhb,
    __half* __restrict__ outact,              // STORE_ALL: [T][B][2H] f16
    float* __restrict__ state,                // [NDIR][B][H][2] f32
    float* __restrict__ lasth,                // !STORE_ALL: [B][H] f32
    int t0_d0, int t0_d1, int tn, int initflag)
{
    constexpr int GPW = 64 / H;
    constexpr int NH  = H / 2;
    constexpr int NGD = 2 * H;

    const int dir  = (NDIR == 2) ? blockIdx.y : 0;
    const int lane = threadIdx.x;
    const int g    = lane / H;
    const int j    = lane - g * H;
    const int b    = blockIdx.x * GPW + g;
    const bool valid = (g < GPW) && (b < B_TOTAL);
    const int bs    = valid ? b : (B_TOTAL - 1);
    const int gbase = (g < GPW ? g : (GPW - 1)) * H;

    const float* w_hh = dir ? whhb : whhf;
    const int t0  = dir ? t0_d1 : t0_d0;
    const int sgn = dir ? -1 : 1;

    f16x2 whh2[4][NH];
#pragma unroll
    for (int q = 0; q < 4; ++q) {
        const int r = q * H + j;
#pragma unroll
        for (int k = 0; k < NH; ++k) {
            f16x2 t;
            t.x = (_Float16)w_hh[r * H + 2 * k];
            t.y = (_Float16)w_hh[r * H + 2 * k + 1];
            whh2[q][k] = t;
        }
    }

    const uint32_t* gp = G + (size_t)dir * dirstride_dw + (size_t)bs * NGD + 2 * j;
    const size_t gstep = (size_t)B_TOTAL * NGD;

    __half* op = nullptr;
    ptrdiff_t opstep = 0;
    if constexpr (STORE_ALL) {
        op = outact + ((size_t)t0 * B_TOTAL + bs) * (2 * H) + dir * H + j;
        opstep = (ptrdiff_t)sgn * (B_TOTAL * 2 * H);
    }

    float* sp = state + (((size_t)dir * B_TOTAL + bs) * H + j) * 2;
    float h, c;
    if (initflag) { h = 0.0f; c = 0.0f; }
    else          { h = sp[0]; c = sp[1]; }

    uint2 qb[8];
#pragma unroll
    for (int s = 0; s < 8; ++s) {      // tn >= 8 always
        qb[s] = *(const uint2*)gp;
        gp += gstep;
    }

    auto step = [&](uint2& slot, bool pf) {
        const uint2 qc = slot;
        // all-gather h across the group via shfl, pack to f16x2
        uint32_t hd[NH];
#pragma unroll
        for (int k = 0; k < NH; ++k) {
            float v0 = __shfl(h, gbase + 2 * k, 64);
            float v1 = __shfl(h, gbase + 2 * k + 1, 64);
            hd[k] = packf2(v0, v1);
        }
        if (pf) { slot = *(const uint2*)gp; gp += gstep; }

        f16x2 lo = __builtin_bit_cast(f16x2, qc.x);
        f16x2 hi = __builtin_bit_cast(f16x2, qc.y);
        float a0 = (float)lo.x, a1 = (float)lo.y;
        float a2 = (float)hi.x, a3 = (float)hi.y;
#pragma unroll
        for (int k = 0; k < NH; ++k) {
            a0 = dot2acc(hd[k], whh2[0][k], a0);
            a1 = dot2acc(hd[k], whh2[1][k], a1);
            a2 = dot2acc(hd[k], whh2[2][k], a2);
            a3 = dot2acc(hd[k], whh2[3][k], a3);
        }
        const float iv = sigm_(a0);
        const float fv = sigm_(a1);
        const float gv = tanh_(a2);
        const float ov = sigm_(a3);
        c = __builtin_fmaf(fv, c, iv * gv);
        h = ov * tanh_(c);
        if constexpr (STORE_ALL) {
            if (valid) *op = __float2half(h);
            op += opstep;
        }
    };

    for (int t = 0; t < tn; t += 8) {   // tn % 8 == 0
#pragma unroll
        for (int u = 0; u < 8; ++u) step(qb[u], t + u + 8 < tn);
    }

    if (valid) { sp[0] = h; sp[1] = c; }   // always persist (L4 chunk 0 needs it)
    if constexpr (!STORE_ALL) {
        if (valid) lasth[b * H + j] = h;
    }
}

// ======================= fused fallback scan (only if ws < 238 MB) =======================
template <int DIN, int H, bool LAYER1, bool STORE_ALL>
__global__ void __launch_bounds__(64, 1) lstm_scan(
    const float* __restrict__ x,
    const __half* __restrict__ inbuf,
    const float* __restrict__ wihf, const float* __restrict__ whhf,
    const float* __restrict__ bihf, const float* __restrict__ bhhf,
    const float* __restrict__ wihb, const float* __restrict__ whhb,
    const float* __restrict__ bihb, const float* __restrict__ bhhb,
    __half* __restrict__ outbuf,
    float* __restrict__ lasth)
{
    constexpr int GPW   = 64 / H;
    constexpr int ND    = DIN / 2;
    constexpr int NH    = H / 2;
    constexpr int HS_DW = (H == 20) ? 12 : 8;

    const int dir  = blockIdx.y;
    const int lane = threadIdx.x;
    const int g    = lane / H;
    const int j    = lane - g * H;
    const int b    = blockIdx.x * GPW + g;
    const bool valid = (g < GPW) && (b < B_TOTAL);
    const int bs   = valid ? b : (B_TOTAL - 1);

    const float* w_ih = dir ? wihb : wihf;
    const float* w_hh = dir ? whhb : whhf;
    const float* b_ih = dir ? bihb : bihf;
    const float* b_hh = dir ? bhhb : bhhf;

    __shared__ uint32_t hsm[GPW + 1][HS_DW];

    f16x2 wih2[4][ND];
    f16x2 whh2[4][NH];
    float bias[4];
#pragma unroll
    for (int q = 0; q < 4; ++q) {
        const int r = q * H + j;
#pragma unroll
        for (int d = 0; d < ND; ++d) {
            f16x2 t;
            t.x = (_Float16)w_ih[r * DIN + 2 * d];
            t.y = (_Float16)w_ih[r * DIN + 2 * d + 1];
            wih2[q][d] = t;
        }
#pragma unroll
        for (int k = 0; k < NH; ++k) {
            f16x2 t;
            t.x = (_Float16)w_hh[r * H + 2 * k];
            t.y = (_Float16)w_hh[r * H + 2 * k + 1];
            whh2[q][k] = t;
        }
        bias[q] = b_ih[r] + b_hh[r];
    }

    const int tstep = dir ? -1 : 1;
    int tt = dir ? (T_TOTAL - 1) : 0;

    __half* op = nullptr;
    ptrdiff_t opstep = 0;
    if constexpr (STORE_ALL) {
        op = outbuf + (size_t)tt * (B_TOTAL * 2 * H) + (size_t)bs * (2 * H) + dir * H + j;
        opstep = (ptrdiff_t)tstep * (B_TOTAL * 2 * H);
    }

    float c = 0.0f;
    float hlast = 0.0f;
    ((__half*)&hsm[g][0])[j] = __float2half(0.0f);
    wavebar();

    auto tail = [&](const uint32_t* hd, float a0, float a1, float a2, float a3) {
#pragma unroll
        for (int k = 0; k < NH; ++k) {
            a0 = dot2acc(hd[k], whh2[0][k], a0);
            a1 = dot2acc(hd[k], whh2[1][k], a1);
            a2 = dot2acc(hd[k], whh2[2][k], a2);
            a3 = dot2acc(hd[k], whh2[3][k], a3);
        }
        const float iv = sigm_(a0);
        const float fv = sigm_(a1);
        const float gv = tanh_(a2);
        const float ov = sigm_(a3);
        c = __builtin_fmaf(fv, c, iv * gv);
        const float h = ov * tanh_(c);
        ((__half*)&hsm[g][0])[j] = __float2half(h);
        wavebar();
        if constexpr (STORE_ALL) {
            if (valid) *op = __float2half(h);
            op += opstep;
        } else {
            hlast = h;
        }
        tt += tstep;
    };

    {
        const ptrdiff_t ipstep = (ptrdiff_t)tstep * (B_TOTAL * ND);
        const uint32_t* ip = (const uint32_t*)inbuf + (size_t)tt * (B_TOTAL * ND) + (size_t)bs * ND;

        uint32_t xb[4][ND];
#pragma unroll
        for (int s = 0; s < 3; ++s) {
#pragma unroll
            for (int d = 0; d < ND; ++d) xb[s][d] = ip[d];
            ip += ipstep;
        }

        auto stp = [&](const uint32_t* xc, uint32_t* xn, bool pf) {
            uint32_t hd[NH];
#pragma unroll
            for (int k = 0; k < NH; ++k) hd[k] = hsm[g][k];

            float a0 = bias[0], a1 = bias[1], a2 = bias[2], a3 = bias[3];
#pragma unroll
            for (int d = 0; d < ND; ++d) {
                a0 = dot2acc(xc[d], wih2[0][d], a0);
                a1 = dot2acc(xc[d], wih2[1][d], a1);
                a2 = dot2acc(xc[d], wih2[2][d], a2);
                a3 = dot2acc(xc[d], wih2[3][d], a3);
            }
            if (pf) {
#pragma unroll
                for (int d = 0; d < ND; ++d) xn[d] = ip[d];
                ip += ipstep;
            }
            tail(hd, a0, a1, a2, a3);
        };

        for (int t = 0; t < T_TOTAL; t += 4) {
            stp(xb[0], xb[3], t + 3 < T_TOTAL);
            stp(xb[1], xb[0], t + 4 < T_TOTAL);
            stp(xb[2], xb[1], t + 5 < T_TOTAL);
            stp(xb[3], xb[2], t + 6 < T_TOTAL);
        }
    }

    if constexpr (!STORE_ALL) {
        if (valid) lasth[b * H + j] = hlast;
    }
}

// L4 backward needed only at t=T-1 (single step from zero state) + FC + sigmoid.
__global__ void final_kernel(const __half* __restrict__ l3out,  // [T][B][20] f16
                             const float* __restrict__ hf4,     // [B][10]
                             const float* __restrict__ w_ih,    // w4b_ih [40][20]
                             const float* __restrict__ b_ih,
                             const float* __restrict__ b_hh,
                             const float* __restrict__ fc_w,    // [20]
                             const float* __restrict__ fc_b,
                             float* __restrict__ out)           // [B]
{
    const int b = blockIdx.x * blockDim.x + threadIdx.x;
    if (b >= B_TOTAL) return;

    float in4[20];
    const __half* p = l3out + (size_t)(T_TOTAL - 1) * (B_TOTAL * 20) + (size_t)b * 20;
#pragma unroll
    for (int i = 0; i < 20; ++i) in4[i] = __half2float(p[i]);

    float z = fc_b[0];
#pragma unroll
    for (int k = 0; k < 10; ++k) z += fc_w[k] * hf4[b * 10 + k];

#pragma unroll
    for (int k = 0; k < 10; ++k) {
        float gi = b_ih[k]      + b_hh[k];
        float gg = b_ih[20 + k] + b_hh[20 + k];
        float go = b_ih[30 + k] + b_hh[30 + k];
#pragma unroll
        for (int i = 0; i < 20; ++i) {
            const float xi = in4[i];
            gi += w_ih[k * 20 + i]        * xi;
            gg += w_ih[(20 + k) * 20 + i] * xi;
            go += w_ih[(30 + k) * 20 + i] * xi;
        }
        const float cc = sigm_(gi) * tanh_(gg);
        const float hb = sigm_(go) * tanh_(cc);
        z += fc_w[10 + k] * hb;
    }
    out[b] = sigm_(z);
}

extern "C" void kernel_launch(void* const* d_in, const int* in_sizes, int n_in,
                              void* d_out, int out_size, void* d_ws, size_t ws_size,
                              hipStream_t stream) {
    const float* x = (const float*)d_in[0];
    auto W = [&](int li, int dr, int k) -> const float* {
        return (const float*)d_in[1 + (li - 1) * 8 + dr * 4 + k];
    };
    const float* fc_w = (const float*)d_in[33];
    const float* fc_b = (const float*)d_in[34];
    float* out = (float*)d_out;

    constexpr size_t MB = 1ull << 20;
    char* w8 = (char*)d_ws;

    if (ws_size >= 238 * MB) {
        // Layout (<= 237 MB, no overlap of live ranges):
        //  A0 [0,80)  A1 [80,160)  G [160, 233.4)  ST [236, 236.32)  HF4 [236.5, ...)
        __half*   A0  = (__half*)w8;
        __half*   A1  = (__half*)(w8 + 80 * MB);
        uint32_t* G   = (uint32_t*)(w8 + 160 * MB);
        float*    ST  = (float*)(w8 + 236 * MB);
        float*    HF4 = (float*)(w8 + 236 * MB + 512 * 1024);

        const int chs[5] = {224, 224, 224, 224, 128};  // all %8==0

        // L1: D=16 (x+lag), H=20 -> A0
        {
            int t0a = 0, t0b = T_TOTAL - 1;
            for (int i = 0; i < 5; ++i) {
                const int tn = chs[i];
                const int ds = tn * B_TOTAL * 40;
                gemmc<16, 20, 2, true><<<dim3(1536, 2), 320, 0, stream>>>(
                    x, nullptr,
                    W(1,0,0), W(1,0,2), W(1,0,3),
                    W(1,1,0), W(1,1,2), W(1,1,3),
                    G, ds, t0a, t0b, tn);
                scan2c<20, 2, true><<<dim3(342, 2), 64, 0, stream>>>(
                    G, ds, W(1,0,1), W(1,1,1), A0, ST, nullptr, t0a, t0b, tn, i == 0);
                t0a += tn; t0b -= tn;
            }
        }
        // L2: D=40, H=20 -> A1
        {
            int t0a = 0, t0b = T_TOTAL - 1;
            for (int i = 0; i < 5; ++i) {
                const int tn = chs[i];
                const int ds = tn * B_TOTAL * 40;
                gemmc<40, 20, 2, false><<<dim3(1536, 2), 320, 0, stream>>>(
                    nullptr, A0,
                    W(2,0,0), W(2,0,2), W(2,0,3),
                    W(2,1,0), W(2,1,2), W(2,1,3),
                    G, ds, t0a, t0b, tn);
                scan2c<20, 2, true><<<dim3(342, 2), 64, 0, stream>>>(
                    G, ds, W(2,0,1), W(2,1,1), A1, ST, nullptr, t0a, t0b, tn, i == 0);
                t0a += tn; t0b -= tn;
            }
        }
        // L3: D=40, H=10 -> A0[0,40MB)
        {
            int t0a = 0, t0b = T_TOTAL - 1;
            for (int i = 0; i < 5; ++i) {
                const int tn = chs[i];
                const int ds = tn * B_TOTAL * 20;
                gemmc<40, 10, 2, false><<<dim3(1536, 2), 320, 0, stream>>>(
                    nullptr, A1,
                    W(3,0,0), W(3,0,2), W(3,0,3),
                    W(3,1,0), W(3,1,2), W(3,1,3),
                    G, ds, t0a, t0b, tn);
                scan2c<10, 2, true><<<dim3(171, 2), 64, 0, stream>>>(
                    G, ds, W(3,0,1), W(3,1,1), A0, ST, nullptr, t0a, t0b, tn, i == 0);
                t0a += tn; t0b -= tn;
            }
        }
        // L4 fwd only: D=20, H=10, 2 chunks of 512 (G chunk 40 MB)
        for (int i = 0; i < 2; ++i) {
            gemmc<20, 10, 1, false><<<dim3(1536, 1), 320, 0, stream>>>(
                nullptr, A0,
                W(4,0,0), W(4,0,2), W(4,0,3),
                W(4,0,0), W(4,0,2), W(4,0,3),
                G, 0, 512 * i, 0, 512);
            scan2c<10, 1, false><<<dim3(171, 1), 64, 0, stream>>>(
                G, 0, W(4,0,1), W(4,0,1), nullptr, ST, HF4, 512 * i, 0, 512, i == 0);
        }

        final_kernel<<<dim3(4, 1, 1), 256, 0, stream>>>(
            A0, HF4, W(4,1,0), W(4,1,2), W(4,1,3), fc_w, fc_b, out);
    } else {
        // 160-MB fallback (overlays FIXED: tn=224 chunks keep G1 < ST1)
        __half*   A0  = (__half*)w8;
        __half*   A1  = (__half*)(w8 + 80 * MB);
        uint32_t* G1  = (uint32_t*)(w8 + 80 * MB);     // [80, 153.4)
        float*    ST1 = (float*)(w8 + 156 * MB);
        uint32_t* G3  = (uint32_t*)(w8 + 40 * MB);     // [40, 76.7)
        float*    ST3 = (float*)(w8 + 78 * MB);
        float*    HF4 = (float*)(w8 + 79 * MB);
        uint32_t* G4  = (uint32_t*)(w8 + 80 * MB);     // full-T, 80 MB

        const int chs[5] = {224, 224, 224, 224, 128};

        {   // L1 -> A0, G in A1 region
            int t0a = 0, t0b = T_TOTAL - 1;
            for (int i = 0; i < 5; ++i) {
                const int tn = chs[i];
                const int ds = tn * B_TOTAL * 40;
                gemmc<16, 20, 2, true><<<dim3(1536, 2), 320, 0, stream>>>(
                    x, nullptr,
                    W(1,0,0), W(1,0,2), W(1,0,3),
                    W(1,1,0), W(1,1,2), W(1,1,3),
                    G1, ds, t0a, t0b, tn);
                scan2c<20, 2, true><<<dim3(342, 2), 64, 0, stream>>>(
                    G1, ds, W(1,0,1), W(1,1,1), A0, ST1, nullptr, t0a, t0b, tn, i == 0);
                t0a += tn; t0b -= tn;
            }
        }
        // L2 fused (no room for its G)
        lstm_scan<40, 20, false, true><<<dim3(342, 2), 64, 0, stream>>>(
            nullptr, A0,
            W(2,0,0), W(2,0,1), W(2,0,2), W(2,0,3),
            W(2,1,0), W(2,1,1), W(2,1,2), W(2,1,3),
            A1, nullptr);
        {   // L3 -> A0[0,40), G in A0[40,76.7)
            int t0a = 0, t0b = T_TOTAL - 1;
            for (int i = 0; i < 5; ++i) {
                const int tn = chs[i];
                const int ds = tn * B_TOTAL * 20;
                gemmc<40, 10, 2, false><<<dim3(1536, 2), 320, 0, stream>>>(
                    nullptr, A1,
                    W(3,0,0), W(3,0,2), W(3,0,3),
                    W(3,1,0), W(3,1,2), W(3,1,3),
                    G3, ds, t0a, t0b, tn);
                scan2c<10, 2, true><<<dim3(171, 2), 64, 0, stream>>>(
                    G3, ds, W(3,0,1), W(3,1,1), A0, ST3, nullptr, t0a, t0b, tn, i == 0);
                t0a += tn; t0b -= tn;
            }
        }
        // L4 fwd: full-T G in A1 region
        gemmc<20, 10, 1, false><<<dim3(1536, 1), 320, 0, stream>>>(
            nullptr, A0,
            W(4,0,0), W(4,0,2), W(4,0,3),
            W(4,0,0), W(4,0,2), W(4,0,3),
            G4, 0, 0, 0, T_TOTAL);
        scan2c<10, 1, false><<<dim3(171, 1), 64, 0, stream>>>(
            G4, 0, W(4,0,1), W(4,0,1), nullptr, ST3, HF4, 0, 0, T_TOTAL, 1);

        final_kernel<<<dim3(4, 1, 1), 256, 0, stream>>>(
            A0, HF4, W(4,1,0), W(4,1,2), W(4,1,3), fc_w, fc_b, out);
    }
}

// Round 8
// 2016.485 us; speedup vs baseline: 1.2503x; 1.2058x over previous
//
#include <hip/hip_runtime.h>
#include <hip/hip_fp16.h>
#include <stdint.h>

#define B_TOTAL 1024
#define T_TOTAL 1024
#define LOG2E 1.44269504088896f

typedef _Float16 f16x2 __attribute__((ext_vector_type(2)));

__device__ __forceinline__ float dot2acc(uint32_t xw, f16x2 w, float acc) {
#if __has_builtin(__builtin_amdgcn_fdot2)
    return __builtin_amdgcn_fdot2(__builtin_bit_cast(f16x2, xw), w, acc, false);
#else
    f16x2 xv = __builtin_bit_cast(f16x2, xw);
    return acc + (float)xv.x * (float)w.x + (float)xv.y * (float)w.y;
#endif
}

__device__ __forceinline__ uint32_t packf2(float a, float b) {
    f16x2 t;
    t.x = (_Float16)a;
    t.y = (_Float16)b;
    return __builtin_bit_cast(uint32_t, t);
}

__device__ __forceinline__ float sigm_(float z) {
    float e = __builtin_amdgcn_exp2f(-LOG2E * z);
    return __builtin_amdgcn_rcpf(1.0f + e);
}
__device__ __forceinline__ float tanh_(float z) {
    float e = __builtin_amdgcn_exp2f((2.0f * LOG2E) * z);
    float r = __builtin_amdgcn_rcpf(1.0f + e);
    return __builtin_fmaf(-2.0f, r, 1.0f);
}

__device__ __forceinline__ void wavebar() {
#if __has_builtin(__builtin_amdgcn_wave_barrier)
    __builtin_amdgcn_wave_barrier();
#endif
}

// Fused bidirectional LSTM scan, dir-packed lanes.
// lane = (g, dir, j): both directions of a batch live in ONE wave -> 2
// independent recurrence chains interleave in the latency shadow, and the
// grid grows to 1024/GPB blocks (4 waves/CU at GPB=1, vs 2.67 before).
// All 4 gates of unit j in one lane; weights in VGPRs; h exchange via LDS
// f16 row (1 ds_write_b16 + 2-3 vector reads); every dot chain split in two.
template <int DIN, int H, int NDIR, int GPB, bool LAYER1, bool STORE_ALL>
__global__ void __launch_bounds__(64, 1) lstm_fused(
    const float* __restrict__ x,              // LAYER1: [B][T][8] f32
    const __half* __restrict__ inbuf,         // else:   [T][B][DIN] f16
    const float* __restrict__ wihf, const float* __restrict__ whhf,
    const float* __restrict__ bihf, const float* __restrict__ bhhf,
    const float* __restrict__ wihb, const float* __restrict__ whhb,
    const float* __restrict__ bihb, const float* __restrict__ bhhb,
    __half* __restrict__ outbuf,              // STORE_ALL: [T][B][2H] f16
    float* __restrict__ lasth)                // !STORE_ALL: [B][H] f32
{
    constexpr int LPG = NDIR * H;          // lanes per batch group
    constexpr int NL  = GPB * LPG;         // active lanes
    constexpr int ND  = DIN / 2;           // input dwords (f16 pairs)
    constexpr int NH  = H / 2;             // h dwords
    constexpr int NHL = NH / 2;            // split point of h chain
    constexpr int HSP = (NH + 3) & ~3;     // padded LDS row (dw), 16B-aligned

    const int lane = threadIdx.x;
    const bool act = lane < NL;
    const int la   = act ? lane : 0;
    const int g    = la / LPG;
    const int rr   = la % LPG;
    const int dir  = (NDIR == 2) ? (rr / H) : 0;
    const int j    = (NDIR == 2) ? (rr % H) : rr;
    const int b    = blockIdx.x * GPB + g;        // grids divide B exactly
    const int sgn  = dir ? -1 : 1;
    int tt         = dir ? (T_TOTAL - 1) : 0;

    const float* w_ih = dir ? wihb : wihf;
    const float* w_hh = dir ? whhb : whhf;
    const float* b_ih = dir ? bihb : bihf;
    const float* b_hh = dir ? bhhb : bhhf;

    __shared__ uint32_t hsm[GPB][NDIR][HSP];
    uint32_t* hrow = &hsm[g][dir][0];
    __half*   hhlf = (__half*)hrow;

    // ---- recurrent weights (f16 pairs) + bias ----
    f16x2 whh2[4][NH];
    float bias[4];
#pragma unroll
    for (int q = 0; q < 4; ++q) {
        const int r_ = q * H + j;
#pragma unroll
        for (int k = 0; k < NH; ++k) {
            f16x2 t;
            t.x = (_Float16)w_hh[r_ * H + 2 * k];
            t.y = (_Float16)w_hh[r_ * H + 2 * k + 1];
            whh2[q][k] = t;
        }
        bias[q] = b_ih[r_] + b_hh[r_];
    }

    // ---- input weights ----
    float wih1[LAYER1 ? 64 : 1];              // L1: 4 gates x 16 f32
    f16x2 wih2[LAYER1 ? 1 : 4][LAYER1 ? 1 : ND];
    if constexpr (LAYER1) {
#pragma unroll
        for (int q = 0; q < 4; ++q)
#pragma unroll
            for (int i = 0; i < 16; ++i)
                wih1[q * 16 + i] = w_ih[(q * H + j) * 16 + i];
    } else {
#pragma unroll
        for (int q = 0; q < 4; ++q) {
            const int r_ = q * H + j;
#pragma unroll
            for (int d = 0; d < ND; ++d) {
                f16x2 t;
                t.x = (_Float16)w_ih[r_ * DIN + 2 * d];
                t.y = (_Float16)w_ih[r_ * DIN + 2 * d + 1];
                wih2[q][d] = t;
            }
        }
    }

    // output pointer
    __half* op = nullptr;
    ptrdiff_t opstep = 0;
    if constexpr (STORE_ALL) {
        op = outbuf + ((size_t)tt * B_TOTAL + b) * (2 * H) + dir * H + j;
        opstep = (ptrdiff_t)sgn * (B_TOTAL * 2 * H);
    }

    float c = 0.0f, h = 0.0f;
    if (act) hhlf[j] = __float2half(0.0f);
    wavebar();

    // finish a step from x-part halves (xl incl bias) -> update c,h, publish
    auto finish = [&](const float* xl, const float* xh) {
        uint32_t hd[NH];
#pragma unroll
        for (int k = 0; k < NH; ++k) hd[k] = hrow[k];
        float hl[4] = {0, 0, 0, 0}, hh[4] = {0, 0, 0, 0};
#pragma unroll
        for (int k = 0; k < NHL; ++k)
#pragma unroll
            for (int q = 0; q < 4; ++q) hl[q] = dot2acc(hd[k], whh2[q][k], hl[q]);
#pragma unroll
        for (int k = NHL; k < NH; ++k)
#pragma unroll
            for (int q = 0; q < 4; ++q) hh[q] = dot2acc(hd[k], whh2[q][k], hh[q]);
        const float a0 = (xl[0] + xh[0]) + (hl[0] + hh[0]);
        const float a1 = (xl[1] + xh[1]) + (hl[1] + hh[1]);
        const float a2 = (xl[2] + xh[2]) + (hl[2] + hh[2]);
        const float a3 = (xl[3] + xh[3]) + (hl[3] + hh[3]);
        const float iv = sigm_(a0);
        const float fv = sigm_(a1);
        const float gv = tanh_(a2);
        const float ov = sigm_(a3);
        c = __builtin_fmaf(fv, c, iv * gv);
        h = ov * tanh_(c);
        if (act) hhlf[j] = __float2half(h);
        wavebar();
        if constexpr (STORE_ALL) {
            if (act) *op = __float2half(h);
            op += opstep;
        }
    };

    if constexpr (LAYER1) {
        const float* xrow = x + (size_t)b * (T_TOTAL * 8);
        float xcur[8], xlag[8];
        {
            const float* p = xrow + (size_t)tt * 8;
#pragma unroll
            for (int i = 0; i < 8; ++i) xcur[i] = p[i];
            const float* q = xrow + (size_t)(tt - (dir ? 1 : 0)) * 8;
#pragma unroll
            for (int i = 0; i < 8; ++i) xlag[i] = dir ? q[i] : 0.0f;
        }
        for (int t = 0; t < T_TOTAL; ++t) {
            float xl[4], xh[4];
#pragma unroll
            for (int q = 0; q < 4; ++q) {
                float a = bias[q], bsum = 0.0f;
#pragma unroll
                for (int i = 0; i < 8; ++i) {
                    a    = __builtin_fmaf(wih1[q * 16 + i],     xcur[i], a);
                    bsum = __builtin_fmaf(wih1[q * 16 + 8 + i], xlag[i], bsum);
                }
                xl[q] = a; xh[q] = bsum;
            }
            // prefetch the fresh row for the next step
            const int li = dir ? (tt - 2) : (tt + 1);
            const bool ld = (li >= 0) && (li < T_TOTAL);
            float np[8];
            if (ld) {
                const float* p = xrow + (size_t)li * 8;
#pragma unroll
                for (int i = 0; i < 8; ++i) np[i] = p[i];
            } else {
#pragma unroll
                for (int i = 0; i < 8; ++i) np[i] = 0.0f;
            }
            finish(xl, xh);
#pragma unroll
            for (int i = 0; i < 8; ++i) {
                const float nc = dir ? xlag[i] : np[i];
                const float nl = dir ? np[i]   : xcur[i];
                xcur[i] = nc; xlag[i] = nl;
            }
            tt += sgn;
        }
    } else {
        const ptrdiff_t ipstep = (ptrdiff_t)sgn * (B_TOTAL * ND);
        const uint32_t* ip = (const uint32_t*)inbuf + ((size_t)tt * B_TOTAL + b) * ND;

        auto loadrow = [&](uint32_t* dst) {
            if constexpr ((ND % 4) == 0) {
#pragma unroll
                for (int q4 = 0; q4 < ND / 4; ++q4) {
                    uint4 v = ((const uint4*)ip)[q4];
                    dst[4 * q4] = v.x; dst[4 * q4 + 1] = v.y;
                    dst[4 * q4 + 2] = v.z; dst[4 * q4 + 3] = v.w;
                }
            } else {
#pragma unroll
                for (int q2 = 0; q2 < ND / 2; ++q2) {
                    uint2 v = ((const uint2*)ip)[q2];
                    dst[2 * q2] = v.x; dst[2 * q2 + 1] = v.y;
                }
                if constexpr (ND & 1) dst[ND - 1] = ip[ND - 1];
            }
            ip += ipstep;
        };

        uint32_t xb[4][ND];
#pragma unroll
        for (int s = 0; s < 3; ++s) loadrow(xb[s]);

        auto step = [&](const uint32_t* xc, uint32_t* xn, bool pf) {
            float xl[4], xh[4];
#pragma unroll
            for (int q = 0; q < 4; ++q) { xl[q] = bias[q]; xh[q] = 0.0f; }
#pragma unroll
            for (int d = 0; d < ND / 2; ++d)
#pragma unroll
                for (int q = 0; q < 4; ++q) xl[q] = dot2acc(xc[d], wih2[q][d], xl[q]);
#pragma unroll
            for (int d = ND / 2; d < ND; ++d)
#pragma unroll
                for (int q = 0; q < 4; ++q) xh[q] = dot2acc(xc[d], wih2[q][d], xh[q]);
            if (pf) loadrow(xn);
            finish(xl, xh);
            tt += sgn;
        };

        for (int t = 0; t < T_TOTAL; t += 4) {
            step(xb[0], xb[3], t + 3 < T_TOTAL);
            step(xb[1], xb[0], t + 4 < T_TOTAL);
            step(xb[2], xb[1], t + 5 < T_TOTAL);
            step(xb[3], xb[2], t + 6 < T_TOTAL);
        }
    }

    if constexpr (!STORE_ALL) {
        if (act) lasth[b * H + j] = h;
    }
}

// L4 backward needed only at t=T-1 (single step from zero state) + FC + sigmoid.
__global__ void final_kernel(const __half* __restrict__ l3out,  // [T][B][20] f16
                             const float* __restrict__ hf4,     // [B][10]
                             const float* __restrict__ w_ih,    // w4b_ih [40][20]
                             const float* __restrict__ b_ih,
                             const float* __restrict__ b_hh,
                             const float* __restrict__ fc_w,    // [20]
                             const float* __restrict__ fc_b,
                             float* __restrict__ out)           // [B]
{
    const int b = blockIdx.x * blockDim.x + threadIdx.x;
    if (b >= B_TOTAL) return;

    float in4[20];
    const __half* p = l3out + (size_t)(T_TOTAL - 1) * (B_TOTAL * 20) + (size_t)b * 20;
#pragma unroll
    for (int i = 0; i < 20; ++i) in4[i] = __half2float(p[i]);

    float z = fc_b[0];
#pragma unroll
    for (int k = 0; k < 10; ++k) z += fc_w[k] * hf4[b * 10 + k];

#pragma unroll
    for (int k = 0; k < 10; ++k) {
        float gi = b_ih[k]      + b_hh[k];
        float gg = b_ih[20 + k] + b_hh[20 + k];
        float go = b_ih[30 + k] + b_hh[30 + k];
#pragma unroll
        for (int i = 0; i < 20; ++i) {
            const float xi = in4[i];
            gi += w_ih[k * 20 + i]        * xi;
            gg += w_ih[(20 + k) * 20 + i] * xi;
            go += w_ih[(30 + k) * 20 + i] * xi;
        }
        const float cc = sigm_(gi) * tanh_(gg);
        const float hb = sigm_(go) * tanh_(cc);
        z += fc_w[10 + k] * hb;
    }
    out[b] = sigm_(z);
}

extern "C" void kernel_launch(void* const* d_in, const int* in_sizes, int n_in,
                              void* d_out, int out_size, void* d_ws, size_t ws_size,
                              hipStream_t stream) {
    const float* x = (const float*)d_in[0];
    auto W = [&](int li, int dr, int k) -> const float* {
        return (const float*)d_in[1 + (li - 1) * 8 + dr * 4 + k];
    };
    const float* fc_w = (const float*)d_in[33];
    const float* fc_b = (const float*)d_in[34];
    float* out = (float*)d_out;

    constexpr size_t MB = 1ull << 20;
    char* w8 = (char*)d_ws;
    // ws: A0 [0,80MB) act, A1 [80,160MB) act, HF4 at 160MB (40KB). ws >= 161MB.
    __half* A0  = (__half*)w8;
    __half* A1  = (__half*)(w8 + 80 * MB);
    float*  HF4 = (float*)(w8 + 160 * MB);

    // L1: D=16 (x+lag), H=20, dir-packed -> A0
    lstm_fused<16, 20, 2, 1, true, true><<<1024, 64, 0, stream>>>(
        x, nullptr,
        W(1,0,0), W(1,0,1), W(1,0,2), W(1,0,3),
        W(1,1,0), W(1,1,1), W(1,1,2), W(1,1,3),
        A0, nullptr);

    // L2: D=40, H=20 -> A1
    lstm_fused<40, 20, 2, 1, false, true><<<1024, 64, 0, stream>>>(
        nullptr, A0,
        W(2,0,0), W(2,0,1), W(2,0,2), W(2,0,3),
        W(2,1,0), W(2,1,1), W(2,1,2), W(2,1,3),
        A1, nullptr);

    // L3: D=40, H=10 -> A0[0,40MB)
    lstm_fused<40, 10, 2, 1, false, true><<<1024, 64, 0, stream>>>(
        nullptr, A1,
        W(3,0,0), W(3,0,1), W(3,0,2), W(3,0,3),
        W(3,1,0), W(3,1,1), W(3,1,2), W(3,1,3),
        A0, nullptr);

    // L4 forward only: D=20, H=10, 2 batches/wave -> HF4
    lstm_fused<20, 10, 1, 2, false, false><<<512, 64, 0, stream>>>(
        nullptr, A0,
        W(4,0,0), W(4,0,1), W(4,0,2), W(4,0,3),
        W(4,0,0), W(4,0,1), W(4,0,2), W(4,0,3), // dir=1 unused
        nullptr, HF4);

    // L4 backward single step + FC + sigmoid
    final_kernel<<<dim3(4, 1, 1), 256, 0, stream>>>(
        A0, HF4, W(4,1,0), W(4,1,2), W(4,1,3), fc_w, fc_b, out);
}